// Round 1
// baseline (371.796 us; speedup 1.0000x reference)
//
#include <hip/hip_runtime.h>

#define BB 4
#define QQ 256
#define VV 2048
#define HH 512
#define UU 128

// exp(x) = exp2(x * LOG2E); tanh arg scale folded into projections: C2E = 2*log2(e)
#define C2E   2.8853900817779268f
#define LOG2E 1.4426950408889634f

// ---------------------------------------------------------------------------
// Projection GEMM: O[r][u] = scale * sum_h A[r][h] * W[h][u]
// A: [rows][512], W: [512][128], O: [rows][128]. 64 rows per block, 256 thr.
// ---------------------------------------------------------------------------
__global__ __launch_bounds__(256) void proj_kernel(const float* __restrict__ A,
                                                   const float* __restrict__ W,
                                                   float* __restrict__ O,
                                                   float scale) {
    __shared__ float As[64 * 18];   // [row][k] pad 18 (even -> aligned float2)
    __shared__ float Ws[16 * 128];  // [k][u]
    const int tid = threadIdx.x;
    const int rowbase = blockIdx.x * 64;
    const int tx = tid & 31, ty = tid >> 5;

    float acc[8][4];
#pragma unroll
    for (int j = 0; j < 8; j++)
#pragma unroll
        for (int i = 0; i < 4; i++) acc[j][i] = 0.0f;

    for (int k0 = 0; k0 < HH; k0 += 16) {
        // stage A tile: 64 rows x 16 k
        {
            const int rl = tid >> 2, kk4 = (tid & 3) * 4;
            float4 a = *(const float4*)&A[((size_t)(rowbase + rl)) * HH + k0 + kk4];
            *(float2*)&As[rl * 18 + kk4]     = make_float2(a.x, a.y);
            *(float2*)&As[rl * 18 + kk4 + 2] = make_float2(a.z, a.w);
        }
        // stage W tile: 16 k x 128 u
#pragma unroll
        for (int t = 0; t < 2; t++) {
            const int f = tid + t * 256;
            const int kk = f >> 5, u4 = (f & 31) * 4;
            *(float4*)&Ws[kk * 128 + u4] = *(const float4*)&W[((size_t)(k0 + kk)) * UU + u4];
        }
        __syncthreads();
#pragma unroll
        for (int kk = 0; kk < 16; kk += 2) {
            float4 w0 = *(const float4*)&Ws[kk * 128 + tx * 4];
            float4 w1 = *(const float4*)&Ws[(kk + 1) * 128 + tx * 4];
#pragma unroll
            for (int j = 0; j < 8; j++) {
                const int rl = ty + j * 8;
                float2 a = *(const float2*)&As[rl * 18 + kk];
                acc[j][0] += a.x * w0.x + a.y * w1.x;
                acc[j][1] += a.x * w0.y + a.y * w1.y;
                acc[j][2] += a.x * w0.z + a.y * w1.z;
                acc[j][3] += a.x * w0.w + a.y * w1.w;
            }
        }
        __syncthreads();
    }
#pragma unroll
    for (int j = 0; j < 8; j++) {
        const int r = rowbase + ty + j * 8;
        float4 o;
        o.x = acc[j][0] * scale; o.y = acc[j][1] * scale;
        o.z = acc[j][2] * scale; o.w = acc[j][3] * scale;
        *(float4*)&O[(size_t)r * UU + tx * 4] = o;
    }
}

// ---------------------------------------------------------------------------
// Transpose pv: [B][V][U] -> [B][U][V], 32x32 LDS tiles
// grid = B * (V/32) * (U/32) = 4*64*4 = 1024
// ---------------------------------------------------------------------------
__global__ __launch_bounds__(256) void transpose_kernel(const float* __restrict__ in,
                                                        float* __restrict__ out) {
    __shared__ float s[32][33];
    const int bid = blockIdx.x;
    const int ut = bid & 3, vt = (bid >> 2) & 63, b = bid >> 8;
    const int u0 = ut * 32, v0 = vt * 32;
#pragma unroll
    for (int k = 0; k < 4; k++) {
        const int lin = threadIdx.x + k * 256;
        const int vr = lin >> 5, uc = lin & 31;
        s[vr][uc] = in[((size_t)(b * VV + v0 + vr)) * UU + u0 + uc];
    }
    __syncthreads();
#pragma unroll
    for (int k = 0; k < 4; k++) {
        const int lin = threadIdx.x + k * 256;
        const int ur = lin >> 5, vc = lin & 31;
        out[((size_t)(b * UU + u0 + ur)) * VV + v0 + vc] = s[vc][ur];
    }
}

// ---------------------------------------------------------------------------
// Scores: scores[b][q][v] = sum_u v[u]*tanh(pq+pv)
//       = sum_u v[u] - sum_u (2 v[u]) * rcp(1 + exp2(pqc+pvc))
// block: (b, 8 q, 256 v). grid = 4*32*8 = 1024
// ---------------------------------------------------------------------------
__global__ __launch_bounds__(256) void scores_kernel(const float* __restrict__ pqc,
                                                     const float* __restrict__ pvcT,
                                                     const float* __restrict__ vvec,
                                                     float* __restrict__ scores) {
    __shared__ float pqs[8 * 128];
    __shared__ float wv[128];
    const int tid = threadIdx.x;
    const int bid = blockIdx.x;
    const int vb = bid & 7, qb = (bid >> 3) & 31, b = bid >> 8;
    const int qbase = qb * 8, vbase = vb * 256;
    {
        const int lin = tid * 4;
        const int q = lin >> 7, u = lin & 127;
        *(float4*)&pqs[q * 128 + u] =
            *(const float4*)&pqc[((size_t)(b * QQ + qbase + q)) * UU + u];
    }
    if (tid < 128) wv[tid] = 2.0f * vvec[tid];
    __syncthreads();

    float vsum = 0.0f;
    for (int u = 0; u < UU; u++) vsum += wv[u];
    vsum *= 0.5f;  // = sum_u v[u]

    float acc[8];
#pragma unroll
    for (int q = 0; q < 8; q++) acc[q] = 0.0f;

    const float* pvp = pvcT + (size_t)b * UU * VV + vbase + tid;
    for (int u = 0; u < UU; u++) {
        const float pv = pvp[(size_t)u * VV];
        const float wu = wv[u];
#pragma unroll
        for (int q = 0; q < 8; q++) {
            const float s = pqs[q * 128 + u] + pv;
            const float t = __builtin_amdgcn_exp2f(s);
            acc[q] = fmaf(wu, __builtin_amdgcn_rcpf(1.0f + t), acc[q]);
        }
    }
#pragma unroll
    for (int q = 0; q < 8; q++)
        scores[((size_t)(b * QQ + qbase + q)) * VV + vbase + tid] = vsum - acc[q];
}

// ---------------------------------------------------------------------------
// Softmax over V + out[b][q][h] = sum_v attn * values[b][v][h]
// block: (b, 8 q, quarter of V=512). grid = 4*32*4 = 512. atomicAdd into out.
// ---------------------------------------------------------------------------
__global__ __launch_bounds__(256) void softmax_out_kernel(const float* __restrict__ scores,
                                                          const float* __restrict__ values,
                                                          float* __restrict__ out) {
    __shared__ float att[8][512];
    __shared__ float ms[8], ils[8];
    const int tid = threadIdx.x;
    const int bid = blockIdx.x;
    const int quarter = bid & 3, qb = (bid >> 2) & 31, b = bid >> 7;
    const int qbase = qb * 8, vbase = quarter * 512;
    const int g = tid >> 5, l = tid & 31;

    // online softmax stats over full V for q = g (32 lanes each)
    const float* sc = scores + ((size_t)(b * QQ + qbase + g)) * VV;
    float m = -1e30f, lsum = 0.0f;
    for (int v = l; v < VV; v += 32) {
        const float s = sc[v];
        const float nm = fmaxf(m, s);
        lsum = lsum * __builtin_amdgcn_exp2f((m - nm) * LOG2E) +
               __builtin_amdgcn_exp2f((s - nm) * LOG2E);
        m = nm;
    }
#pragma unroll
    for (int off = 16; off > 0; off >>= 1) {
        const float m2 = __shfl_xor(m, off, 32);
        const float l2 = __shfl_xor(lsum, off, 32);
        const float nm = fmaxf(m, m2);
        lsum = lsum * __builtin_amdgcn_exp2f((m - nm) * LOG2E) +
               l2 * __builtin_amdgcn_exp2f((m2 - nm) * LOG2E);
        m = nm;
    }
    if (l == 0) { ms[g] = m; ils[g] = __builtin_amdgcn_rcpf(lsum); }
    __syncthreads();

    // attn weights for our V-quarter (already divided by denom)
#pragma unroll
    for (int k = 0; k < 16; k++) {
        const int lin = tid + k * 256;
        const int q = lin >> 9, v = lin & 511;
        const float* scq = scores + ((size_t)(b * QQ + qbase + q)) * VV;
        att[q][v] = __builtin_amdgcn_exp2f((scq[vbase + v] - ms[q]) * LOG2E) * ils[q];
    }
    __syncthreads();

    // weighted sum of values over our V-quarter; thread owns h = 2*tid, 2*tid+1
    float acc0[8], acc1[8];
#pragma unroll
    for (int q = 0; q < 8; q++) { acc0[q] = 0.0f; acc1[q] = 0.0f; }
    const float* vp = values + ((size_t)(b * VV + vbase)) * HH + 2 * tid;
    for (int vv = 0; vv < 512; vv += 4) {
        const float2 w0 = *(const float2*)(vp + (size_t)(vv + 0) * HH);
        const float2 w1 = *(const float2*)(vp + (size_t)(vv + 1) * HH);
        const float2 w2 = *(const float2*)(vp + (size_t)(vv + 2) * HH);
        const float2 w3 = *(const float2*)(vp + (size_t)(vv + 3) * HH);
#pragma unroll
        for (int q = 0; q < 8; q++) {
            const float4 a = *(const float4*)&att[q][vv];
            acc0[q] += a.x * w0.x + a.y * w1.x + a.z * w2.x + a.w * w3.x;
            acc1[q] += a.x * w0.y + a.y * w1.y + a.z * w2.y + a.w * w3.y;
        }
    }
#pragma unroll
    for (int q = 0; q < 8; q++) {
        float* op = out + ((size_t)(b * QQ + qbase + q)) * HH + 2 * tid;
        atomicAdd(op, acc0[q]);
        atomicAdd(op + 1, acc1[q]);
    }
}

// ---------------------------------------------------------------------------
extern "C" void kernel_launch(void* const* d_in, const int* in_sizes, int n_in,
                              void* d_out, int out_size, void* d_ws, size_t ws_size,
                              hipStream_t stream) {
    const float* queries = (const float*)d_in[0];  // [B,Q,H]
    const float* values  = (const float*)d_in[1];  // [B,V,H]
    const float* w1      = (const float*)d_in[2];  // [H,U]
    const float* w2      = (const float*)d_in[3];  // [H,U]
    const float* vvec    = (const float*)d_in[4];  // [U]
    float* out = (float*)d_out;

    // ws layout (floats): pqc | pvcT | pvc ; scores overlaps pvc (pvc dead then)
    float* ws = (float*)d_ws;
    float* pqc    = ws;                          // B*Q*U   = 131072
    float* pvcT   = pqc + BB * QQ * UU;          // B*U*V   = 1048576
    float* pvc    = pvcT + (size_t)BB * UU * VV; // B*V*U   = 1048576
    float* scores = pvc;                         // B*Q*V   = 2097152 (reuses pvc+)

    hipMemsetAsync(d_out, 0, (size_t)out_size * sizeof(float), stream);

    proj_kernel<<<BB * QQ / 64, 256, 0, stream>>>(queries, w1, pqc, C2E);
    proj_kernel<<<BB * VV / 64, 256, 0, stream>>>(values, w2, pvc, C2E);
    transpose_kernel<<<BB * (VV / 32) * (UU / 32), 256, 0, stream>>>(pvc, pvcT);
    scores_kernel<<<BB * (QQ / 8) * (VV / 256), 256, 0, stream>>>(pqc, pvcT, vvec, scores);
    softmax_out_kernel<<<BB * (QQ / 8) * 4, 256, 0, stream>>>(scores, values, out);
}

// Round 2
// 336.878 us; speedup vs baseline: 1.1037x; 1.1037x over previous
//
#include <hip/hip_runtime.h>

#define BB 4
#define QQ 256
#define VV 2048
#define HH 512
#define UU 128

// exp(x) = exp2(x*LOG2E); tanh arg scale folded into projections: C2E = 2*log2(e)
#define C2E   2.8853900817779268f
#define LOG2E 1.4426950408889634f

__device__ __forceinline__ void fma4(float4& a, float s, const float4& w) {
    a.x = fmaf(s, w.x, a.x);
    a.y = fmaf(s, w.y, a.y);
    a.z = fmaf(s, w.z, a.z);
    a.w = fmaf(s, w.w, a.w);
}

// ---------------------------------------------------------------------------
// Merged projection GEMM: O[r][u] = C2E * sum_h A[r][h]*W[h][u]
// blocks 0..2047: values (8192 rows / 4); blocks 2048..2303: queries (1024/4)
// 4 rows/block, 256 threads, thread owns 2 u (float2). W read direct (L1/L2).
// ---------------------------------------------------------------------------
__global__ __launch_bounds__(256) void proj_kernel(const float* __restrict__ queries,
                                                   const float* __restrict__ values,
                                                   const float* __restrict__ w1,
                                                   const float* __restrict__ w2,
                                                   float* __restrict__ pqc,
                                                   float* __restrict__ pvc) {
    const int bid = blockIdx.x;
    const float* A; const float* W; float* O; int rowbase;
    if (bid < 2048) { A = values;  W = w2; O = pvc; rowbase = bid * 4; }
    else            { A = queries; W = w1; O = pqc; rowbase = (bid - 2048) * 4; }

    const int tid = threadIdx.x;
    const int r  = tid >> 6;          // 0..3 (wave-uniform)
    const int u2 = (tid & 63) * 2;    // 0..126

    __shared__ float As[4][32];
    float2 acc = make_float2(0.0f, 0.0f);

    for (int k0 = 0; k0 < HH; k0 += 32) {
        if (tid < 128)
            As[tid >> 5][tid & 31] = A[(size_t)(rowbase + (tid >> 5)) * HH + k0 + (tid & 31)];
        __syncthreads();
#pragma unroll
        for (int kk4 = 0; kk4 < 8; kk4++) {
            const float4 a4 = *(const float4*)&As[r][kk4 * 4];
            const float* wrow = &W[(size_t)(k0 + kk4 * 4) * UU + u2];
            const float2 w0 = *(const float2*)&wrow[0];
            const float2 wb = *(const float2*)&wrow[UU];
            const float2 wc = *(const float2*)&wrow[2 * UU];
            const float2 wd = *(const float2*)&wrow[3 * UU];
            acc.x += a4.x * w0.x + a4.y * wb.x + a4.z * wc.x + a4.w * wd.x;
            acc.y += a4.x * w0.y + a4.y * wb.y + a4.z * wc.y + a4.w * wd.y;
        }
        __syncthreads();
    }
    float2 o = make_float2(acc.x * C2E, acc.y * C2E);
    *(float2*)&O[(size_t)(rowbase + r) * UU + u2] = o;
}

// ---------------------------------------------------------------------------
// Transpose pv: [B][V][U] -> [B][U][V], 32x32 LDS tiles. grid = 1024
// ---------------------------------------------------------------------------
__global__ __launch_bounds__(256) void transpose_kernel(const float* __restrict__ in,
                                                        float* __restrict__ out) {
    __shared__ float s[32][33];
    const int bid = blockIdx.x;
    const int ut = bid & 3, vt = (bid >> 2) & 63, b = bid >> 8;
    const int u0 = ut * 32, v0 = vt * 32;
#pragma unroll
    for (int k = 0; k < 4; k++) {
        const int lin = threadIdx.x + k * 256;
        const int vr = lin >> 5, uc = lin & 31;
        s[vr][uc] = in[((size_t)(b * VV + v0 + vr)) * UU + u0 + uc];
    }
    __syncthreads();
#pragma unroll
    for (int k = 0; k < 4; k++) {
        const int lin = threadIdx.x + k * 256;
        const int ur = lin >> 5, vc = lin & 31;
        out[((size_t)(b * UU + u0 + ur)) * VV + v0 + vc] = s[vc][ur];
    }
}

// ---------------------------------------------------------------------------
// Scores -> exp(scores). tile: 8 q x 512 v (lane owns 2 v). grid = 4*32*4 = 512
// esc[b][q][v] = exp( sum_u v[u] - sum_u 2 v[u] * rcp(1 + exp2(pqc+pvc)) )
// ---------------------------------------------------------------------------
__global__ __launch_bounds__(256) void scores_kernel(const float* __restrict__ pqc,
                                                     const float* __restrict__ pvcT,
                                                     const float* __restrict__ vvec,
                                                     float* __restrict__ esc) {
    __shared__ float pqs[8 * 128];
    __shared__ float wv[128];
    const int tid = threadIdx.x;
    const int bid = blockIdx.x;
    const int vb = bid & 3, qb = (bid >> 2) & 31, b = bid >> 7;
    const int qbase = qb * 8, vbase = vb * 512;
    {
        const int lin = tid * 4;            // = q*128 + u
        const int q = lin >> 7, u = lin & 127;
        *(float4*)&pqs[lin] = *(const float4*)&pqc[((size_t)(b * QQ + qbase + q)) * UU + u];
    }
    if (tid < 128) wv[tid] = 2.0f * vvec[tid];
    __syncthreads();

    float vsum = 0.0f;
#pragma unroll
    for (int u4 = 0; u4 < 32; u4++) {
        const float4 t = *(const float4*)&wv[u4 * 4];
        vsum += t.x + t.y + t.z + t.w;
    }
    vsum *= 0.5f;   // = sum_u v[u]

    const int v0 = vbase + tid * 2;
    const float* pvp = pvcT + (size_t)b * UU * VV + v0;

    float2 acc[8];
#pragma unroll
    for (int q = 0; q < 8; q++) acc[q] = make_float2(0.0f, 0.0f);

    for (int u = 0; u < UU; u += 2) {
        const float2 pva = *(const float2*)&pvp[(size_t)u * VV];
        const float2 pvb = *(const float2*)&pvp[(size_t)(u + 1) * VV];
        const float2 wu  = *(const float2*)&wv[u];
#pragma unroll
        for (int q = 0; q < 8; q++) {
            const float2 pq = *(const float2*)&pqs[q * 128 + u];
            const float t0 = __builtin_amdgcn_exp2f(pq.x + pva.x);
            const float t1 = __builtin_amdgcn_exp2f(pq.x + pva.y);
            const float t2 = __builtin_amdgcn_exp2f(pq.y + pvb.x);
            const float t3 = __builtin_amdgcn_exp2f(pq.y + pvb.y);
            acc[q].x = fmaf(wu.x, __builtin_amdgcn_rcpf(1.0f + t0), acc[q].x);
            acc[q].y = fmaf(wu.x, __builtin_amdgcn_rcpf(1.0f + t1), acc[q].y);
            acc[q].x = fmaf(wu.y, __builtin_amdgcn_rcpf(1.0f + t2), acc[q].x);
            acc[q].y = fmaf(wu.y, __builtin_amdgcn_rcpf(1.0f + t3), acc[q].y);
        }
    }
#pragma unroll
    for (int q = 0; q < 8; q++) {
        float2 e;
        e.x = __builtin_amdgcn_exp2f((vsum - acc[q].x) * LOG2E);
        e.y = __builtin_amdgcn_exp2f((vsum - acc[q].y) * LOG2E);
        *(float2*)&esc[((size_t)(b * QQ + qbase + q)) * VV + v0] = e;
    }
}

// ---------------------------------------------------------------------------
// denom[row] = sum_v esc[row][v].  grid = B*Q = 1024, one block per row.
// ---------------------------------------------------------------------------
__global__ __launch_bounds__(256) void denom_kernel(const float* __restrict__ esc,
                                                    float* __restrict__ denom) {
    const int row = blockIdx.x;
    const int tid = threadIdx.x;
    const float* e = esc + (size_t)row * VV;
    float s = 0.0f;
#pragma unroll
    for (int k = 0; k < VV / 256; k++) s += e[tid + k * 256];
#pragma unroll
    for (int off = 32; off > 0; off >>= 1) s += __shfl_xor(s, off, 64);
    __shared__ float r4[4];
    if ((tid & 63) == 0) r4[tid >> 6] = s;
    __syncthreads();
    if (tid == 0) denom[row] = r4[0] + r4[1] + r4[2] + r4[3];
}

// ---------------------------------------------------------------------------
// out[b][q][h] += sum_v (esc/denom) * values[b][v][h]
// block: 4 q x 512-v slice; thread owns 4 h, block split into 2 v-halves.
// grid = 4 b * 64 qb * 4 vs = 1024. LDS-reduce halves, then atomicAdd.
// ---------------------------------------------------------------------------
__global__ __launch_bounds__(256) void out_kernel(const float* __restrict__ esc,
                                                  const float* __restrict__ denom,
                                                  const float* __restrict__ values,
                                                  float* __restrict__ out) {
    __shared__ float att[512 * 4];   // [v][q], 8KB; reused as reduction buffer
    __shared__ float ils[4];
    const int tid = threadIdx.x;
    const int bid = blockIdx.x;
    const int vs = bid & 3, qb = (bid >> 2) & 63, b = bid >> 8;
    const int qbase = qb * 4, vbase = vs * 512;

    if (tid < 4) ils[tid] = __builtin_amdgcn_rcpf(denom[b * QQ + qbase + tid]);
    __syncthreads();
#pragma unroll
    for (int k = 0; k < 8; k++) {
        const int lin = k * 256 + tid;
        const int q = lin >> 9, v = lin & 511;
        att[v * 4 + q] = esc[((size_t)(b * QQ + qbase + q)) * VV + vbase + v] * ils[q];
    }
    __syncthreads();

    const int sub = tid >> 7;          // v-half (wave-uniform)
    const int h0  = (tid & 127) * 4;
    const float* vp = values + ((size_t)(b * VV + vbase + sub * 256)) * HH + h0;

    float4 acc[4];
#pragma unroll
    for (int q = 0; q < 4; q++) acc[q] = make_float4(0.f, 0.f, 0.f, 0.f);

    for (int v = 0; v < 256; v += 2) {
        const float4 a0 = *(const float4*)&att[(sub * 256 + v) * 4];
        const float4 w0 = *(const float4*)&vp[(size_t)v * HH];
        const float4 a1 = *(const float4*)&att[(sub * 256 + v + 1) * 4];
        const float4 w1 = *(const float4*)&vp[(size_t)(v + 1) * HH];
        fma4(acc[0], a0.x, w0); fma4(acc[1], a0.y, w0);
        fma4(acc[2], a0.z, w0); fma4(acc[3], a0.w, w0);
        fma4(acc[0], a1.x, w1); fma4(acc[1], a1.y, w1);
        fma4(acc[2], a1.z, w1); fma4(acc[3], a1.w, w1);
    }

    __syncthreads();   // att dead; reuse as red[128][4q][4h]
    float* red = att;
    if (sub == 1) {
#pragma unroll
        for (int q = 0; q < 4; q++)
            *(float4*)&red[((tid & 127) * 4 + q) * 4] = acc[q];
    }
    __syncthreads();
    if (sub == 0) {
#pragma unroll
        for (int q = 0; q < 4; q++) {
            const float4 p = *(const float4*)&red[((tid & 127) * 4 + q) * 4];
            float* op = out + ((size_t)(b * QQ + qbase + q)) * HH + h0;
            atomicAdd(op + 0, acc[q].x + p.x);
            atomicAdd(op + 1, acc[q].y + p.y);
            atomicAdd(op + 2, acc[q].z + p.z);
            atomicAdd(op + 3, acc[q].w + p.w);
        }
    }
}

// ---------------------------------------------------------------------------
extern "C" void kernel_launch(void* const* d_in, const int* in_sizes, int n_in,
                              void* d_out, int out_size, void* d_ws, size_t ws_size,
                              hipStream_t stream) {
    const float* queries = (const float*)d_in[0];  // [B,Q,H]
    const float* values  = (const float*)d_in[1];  // [B,V,H]
    const float* w1      = (const float*)d_in[2];  // [H,U]
    const float* w2      = (const float*)d_in[3];  // [H,U]
    const float* vvec    = (const float*)d_in[4];  // [U]
    float* out = (float*)d_out;

    // ws (floats): pqc[131072] | pvcT[1048576] | pvc[1048576]
    // esc aliases pvc and extends to 2097152 (pvc dead after transpose).
    // denom[1024] aliases pqc (pqc dead after scores_kernel).
    float* ws    = (float*)d_ws;
    float* pqc   = ws;
    float* denom = ws;
    float* pvcT  = ws + BB * QQ * UU;
    float* pvc   = pvcT + (size_t)BB * UU * VV;
    float* esc   = pvc;

    hipMemsetAsync(d_out, 0, (size_t)out_size * sizeof(float), stream);

    proj_kernel<<<2304, 256, 0, stream>>>(queries, values, w1, w2, pqc, pvc);
    transpose_kernel<<<BB * (VV / 32) * (UU / 32), 256, 0, stream>>>(pvc, pvcT);
    scores_kernel<<<BB * (QQ / 8) * (VV / 512), 256, 0, stream>>>(pqc, pvcT, vvec, esc);
    denom_kernel<<<BB * QQ, 256, 0, stream>>>(esc, denom);
    out_kernel<<<BB * (QQ / 4) * (VV / 512), 256, 0, stream>>>(esc, denom, values, out);
}

// Round 3
// 239.234 us; speedup vs baseline: 1.5541x; 1.4082x over previous
//
#include <hip/hip_runtime.h>

#define BB 4
#define QQ 256
#define VV 2048
#define HH 512
#define UU 128

// exp(x) = exp2(x*LOG2E); tanh arg scale folded into projections: C2E = 2*log2(e)
#define C2E   2.8853900817779268f
#define LOG2E 1.4426950408889634f

__device__ __forceinline__ void fma4(float4& a, float s, const float4& w) {
    a.x = fmaf(s, w.x, a.x);
    a.y = fmaf(s, w.y, a.y);
    a.z = fmaf(s, w.z, a.z);
    a.w = fmaf(s, w.w, a.w);
}

// ---------------------------------------------------------------------------
// Projection GEMM: O[r][u] = C2E * sum_h A[r][h]*W[h][u]
// 16 rows x 128 u per block, BK=32, W staged in LDS (R2 failure: W from
// global was VMEM-latency-bound at VALUBusy 9%). grid = 9216/16 = 576.
// thread: 2 rows x 4 u. A-tile transposed [k][row] pad 18 (2-way = free).
// ---------------------------------------------------------------------------
__global__ __launch_bounds__(256) void proj_kernel(const float* __restrict__ queries,
                                                   const float* __restrict__ values,
                                                   const float* __restrict__ w1,
                                                   const float* __restrict__ w2,
                                                   float* __restrict__ pqc,
                                                   float* __restrict__ pvc) {
    __shared__ float As[32][18];     // [k][row], padded
    __shared__ float Ws[32 * 128];   // [k][u], 16 KB
    const int bid = blockIdx.x;
    const int rowbase = bid * 16;
    const float* A; const float* W; float* O;
    if (rowbase < BB * VV) {
        A = values + (size_t)rowbase * HH;  W = w2;  O = pvc + (size_t)rowbase * UU;
    } else {
        const int r0 = rowbase - BB * VV;
        A = queries + (size_t)r0 * HH;      W = w1;  O = pqc + (size_t)r0 * UU;
    }

    const int tid = threadIdx.x;
    const int tx = tid & 31;         // u-group: u = tx*4 .. tx*4+3
    const int ty = tid >> 5;         // row-pair: rows 2ty, 2ty+1
    float4 acc0 = make_float4(0.f, 0.f, 0.f, 0.f);
    float4 acc1 = make_float4(0.f, 0.f, 0.f, 0.f);

    for (int k0 = 0; k0 < HH; k0 += 32) {
        if (tid < 128) {             // A tile: 16 rows x 32 k, store transposed
            const int r = tid >> 3, kk4 = (tid & 7) * 4;
            const float4 a = *(const float4*)&A[(size_t)r * HH + k0 + kk4];
            As[kk4 + 0][r] = a.x; As[kk4 + 1][r] = a.y;
            As[kk4 + 2][r] = a.z; As[kk4 + 3][r] = a.w;
        }
#pragma unroll
        for (int t = 0; t < 4; t++) {  // W tile: 32 k x 128 u (1024 float4)
            const int f = tid + t * 256;
            const int kk = f >> 5, u4 = (f & 31) * 4;
            *(float4*)&Ws[kk * 128 + u4] = *(const float4*)&W[(size_t)(k0 + kk) * UU + u4];
        }
        __syncthreads();
#pragma unroll
        for (int kk = 0; kk < 32; kk++) {
            const float2 a = *(const float2*)&As[kk][ty * 2];   // broadcast
            const float4 w = *(const float4*)&Ws[kk * 128 + tx * 4];
            fma4(acc0, a.x, w);
            fma4(acc1, a.y, w);
        }
        __syncthreads();
    }
    float4 o0, o1;
    o0.x = acc0.x * C2E; o0.y = acc0.y * C2E; o0.z = acc0.z * C2E; o0.w = acc0.w * C2E;
    o1.x = acc1.x * C2E; o1.y = acc1.y * C2E; o1.z = acc1.z * C2E; o1.w = acc1.w * C2E;
    *(float4*)&O[(size_t)(ty * 2 + 0) * UU + tx * 4] = o0;
    *(float4*)&O[(size_t)(ty * 2 + 1) * UU + tx * 4] = o1;
}

// ---------------------------------------------------------------------------
// Transpose pv: [B][V][U] -> [B][U][V], 32x32 LDS tiles. grid = 1024
// ---------------------------------------------------------------------------
__global__ __launch_bounds__(256) void transpose_kernel(const float* __restrict__ in,
                                                        float* __restrict__ out) {
    __shared__ float s[32][33];
    const int bid = blockIdx.x;
    const int ut = bid & 3, vt = (bid >> 2) & 63, b = bid >> 8;
    const int u0 = ut * 32, v0 = vt * 32;
#pragma unroll
    for (int k = 0; k < 4; k++) {
        const int lin = threadIdx.x + k * 256;
        const int vr = lin >> 5, uc = lin & 31;
        s[vr][uc] = in[((size_t)(b * VV + v0 + vr)) * UU + u0 + uc];
    }
    __syncthreads();
#pragma unroll
    for (int k = 0; k < 4; k++) {
        const int lin = threadIdx.x + k * 256;
        const int ur = lin >> 5, vc = lin & 31;
        out[((size_t)(b * UU + u0 + ur)) * VV + v0 + vc] = s[vc][ur];
    }
}

// ---------------------------------------------------------------------------
// Scores -> exp(scores). tile: 4 q x 512 v (lane owns 2 v). grid = 4*64*4=1024
// esc[b][q][v] = exp( sum_u v[u] - sum_u 2 v[u] * rcp(1 + exp2(pqc+pvc)) )
// ---------------------------------------------------------------------------
__global__ __launch_bounds__(256) void scores_kernel(const float* __restrict__ pqc,
                                                     const float* __restrict__ pvcT,
                                                     const float* __restrict__ vvec,
                                                     float* __restrict__ esc) {
    __shared__ float pqs[4 * 128];
    __shared__ float wv[128];
    const int tid = threadIdx.x;
    const int bid = blockIdx.x;
    const int vb = bid & 3, qb = (bid >> 2) & 63, b = bid >> 8;
    const int qbase = qb * 4, vbase = vb * 512;
    {
        const int lin = tid * 2;            // = q*128 + u
        const int q = lin >> 7, u = lin & 127;
        *(float2*)&pqs[lin] = *(const float2*)&pqc[((size_t)(b * QQ + qbase + q)) * UU + u];
    }
    if (tid < 128) wv[tid] = 2.0f * vvec[tid];
    __syncthreads();

    float vsum = 0.0f;
#pragma unroll
    for (int u4 = 0; u4 < 32; u4++) {
        const float4 t = *(const float4*)&wv[u4 * 4];
        vsum += t.x + t.y + t.z + t.w;
    }
    vsum *= 0.5f;   // = sum_u v[u]

    const int v0 = vbase + tid * 2;
    const float* pvp = pvcT + (size_t)b * UU * VV + v0;

    float2 acc[4];
#pragma unroll
    for (int q = 0; q < 4; q++) acc[q] = make_float2(0.0f, 0.0f);

    for (int u = 0; u < UU; u += 2) {
        const float2 pva = *(const float2*)&pvp[(size_t)u * VV];
        const float2 pvb = *(const float2*)&pvp[(size_t)(u + 1) * VV];
        const float2 wu  = *(const float2*)&wv[u];
#pragma unroll
        for (int q = 0; q < 4; q++) {
            const float2 pq = *(const float2*)&pqs[q * 128 + u];
            const float t0 = __builtin_amdgcn_exp2f(pq.x + pva.x);
            const float t1 = __builtin_amdgcn_exp2f(pq.x + pva.y);
            const float t2 = __builtin_amdgcn_exp2f(pq.y + pvb.x);
            const float t3 = __builtin_amdgcn_exp2f(pq.y + pvb.y);
            acc[q].x = fmaf(wu.x, __builtin_amdgcn_rcpf(1.0f + t0), acc[q].x);
            acc[q].y = fmaf(wu.x, __builtin_amdgcn_rcpf(1.0f + t1), acc[q].y);
            acc[q].x = fmaf(wu.y, __builtin_amdgcn_rcpf(1.0f + t2), acc[q].x);
            acc[q].y = fmaf(wu.y, __builtin_amdgcn_rcpf(1.0f + t3), acc[q].y);
        }
    }
#pragma unroll
    for (int q = 0; q < 4; q++) {
        float2 e;
        e.x = __builtin_amdgcn_exp2f((vsum - acc[q].x) * LOG2E);
        e.y = __builtin_amdgcn_exp2f((vsum - acc[q].y) * LOG2E);
        *(float2*)&esc[((size_t)(b * QQ + qbase + q)) * VV + v0] = e;
    }
}

// ---------------------------------------------------------------------------
// denom[row] = sum_v esc[row][v].  grid = B*Q = 1024, one block per row.
// ---------------------------------------------------------------------------
__global__ __launch_bounds__(256) void denom_kernel(const float* __restrict__ esc,
                                                    float* __restrict__ denom) {
    const int row = blockIdx.x;
    const int tid = threadIdx.x;
    const float* e = esc + (size_t)row * VV;
    float s = 0.0f;
#pragma unroll
    for (int k = 0; k < VV / 256; k++) s += e[tid + k * 256];
#pragma unroll
    for (int off = 32; off > 0; off >>= 1) s += __shfl_xor(s, off, 64);
    __shared__ float r4[4];
    if ((tid & 63) == 0) r4[tid >> 6] = s;
    __syncthreads();
    if (tid == 0) denom[row] = r4[0] + r4[1] + r4[2] + r4[3];
}

// ---------------------------------------------------------------------------
// out[b][q][h] += sum_v (esc/denom) * values[b][v][h]
// block: 4 q x 512-v slice; thread owns 4 h, block split into 2 v-halves.
// grid = 1024. v-loop unrolled x4 for VMEM ILP (R1 version latency-bound).
// ---------------------------------------------------------------------------
__global__ __launch_bounds__(256) void out_kernel(const float* __restrict__ esc,
                                                  const float* __restrict__ denom,
                                                  const float* __restrict__ values,
                                                  float* __restrict__ out) {
    __shared__ float att[512 * 4];   // [v][q], 8KB; reused as reduction buffer
    __shared__ float ils[4];
    const int tid = threadIdx.x;
    const int bid = blockIdx.x;
    const int vs = bid & 3, qb = (bid >> 2) & 63, b = bid >> 8;
    const int qbase = qb * 4, vbase = vs * 512;

    if (tid < 4) ils[tid] = __builtin_amdgcn_rcpf(denom[b * QQ + qbase + tid]);
    __syncthreads();
#pragma unroll
    for (int k = 0; k < 8; k++) {
        const int lin = k * 256 + tid;
        const int q = lin >> 9, v = lin & 511;
        att[v * 4 + q] = esc[((size_t)(b * QQ + qbase + q)) * VV + vbase + v] * ils[q];
    }
    __syncthreads();

    const int sub = tid >> 7;          // v-half (wave-uniform)
    const int h0  = (tid & 127) * 4;
    const float* vp = values + ((size_t)(b * VV + vbase + sub * 256)) * HH + h0;

    float4 acc[4];
#pragma unroll
    for (int q = 0; q < 4; q++) acc[q] = make_float4(0.f, 0.f, 0.f, 0.f);

    for (int v = 0; v < 256; v += 4) {
        const float4 w0 = *(const float4*)&vp[(size_t)(v + 0) * HH];
        const float4 w1 = *(const float4*)&vp[(size_t)(v + 1) * HH];
        const float4 w2 = *(const float4*)&vp[(size_t)(v + 2) * HH];
        const float4 w3 = *(const float4*)&vp[(size_t)(v + 3) * HH];
        const float4 a0 = *(const float4*)&att[(sub * 256 + v + 0) * 4];
        const float4 a1 = *(const float4*)&att[(sub * 256 + v + 1) * 4];
        const float4 a2 = *(const float4*)&att[(sub * 256 + v + 2) * 4];
        const float4 a3 = *(const float4*)&att[(sub * 256 + v + 3) * 4];
        fma4(acc[0], a0.x, w0); fma4(acc[1], a0.y, w0);
        fma4(acc[2], a0.z, w0); fma4(acc[3], a0.w, w0);
        fma4(acc[0], a1.x, w1); fma4(acc[1], a1.y, w1);
        fma4(acc[2], a1.z, w1); fma4(acc[3], a1.w, w1);
        fma4(acc[0], a2.x, w2); fma4(acc[1], a2.y, w2);
        fma4(acc[2], a2.z, w2); fma4(acc[3], a2.w, w2);
        fma4(acc[0], a3.x, w3); fma4(acc[1], a3.y, w3);
        fma4(acc[2], a3.z, w3); fma4(acc[3], a3.w, w3);
    }

    __syncthreads();   // att dead; reuse as red[128][4q][4h]
    float* red = att;
    if (sub == 1) {
#pragma unroll
        for (int q = 0; q < 4; q++)
            *(float4*)&red[((tid & 127) * 4 + q) * 4] = acc[q];
    }
    __syncthreads();
    if (sub == 0) {
#pragma unroll
        for (int q = 0; q < 4; q++) {
            const float4 p = *(const float4*)&red[((tid & 127) * 4 + q) * 4];
            float* op = out + ((size_t)(b * QQ + qbase + q)) * HH + h0;
            atomicAdd(op + 0, acc[q].x + p.x);
            atomicAdd(op + 1, acc[q].y + p.y);
            atomicAdd(op + 2, acc[q].z + p.z);
            atomicAdd(op + 3, acc[q].w + p.w);
        }
    }
}

// ---------------------------------------------------------------------------
extern "C" void kernel_launch(void* const* d_in, const int* in_sizes, int n_in,
                              void* d_out, int out_size, void* d_ws, size_t ws_size,
                              hipStream_t stream) {
    const float* queries = (const float*)d_in[0];  // [B,Q,H]
    const float* values  = (const float*)d_in[1];  // [B,V,H]
    const float* w1      = (const float*)d_in[2];  // [H,U]
    const float* w2      = (const float*)d_in[3];  // [H,U]
    const float* vvec    = (const float*)d_in[4];  // [U]
    float* out = (float*)d_out;

    // ws (floats): pqc[131072] | pvcT[1048576] | pvc[1048576]
    // esc aliases pvc and extends to 2097152 (pvc dead after transpose).
    // denom[1024] aliases pqc (pqc dead after scores_kernel).
    float* ws    = (float*)d_ws;
    float* pqc   = ws;
    float* denom = ws;
    float* pvcT  = ws + BB * QQ * UU;
    float* pvc   = pvcT + (size_t)BB * UU * VV;
    float* esc   = pvc;

    hipMemsetAsync(d_out, 0, (size_t)out_size * sizeof(float), stream);

    proj_kernel<<<(BB * VV + BB * QQ) / 16, 256, 0, stream>>>(queries, values, w1, w2, pqc, pvc);
    transpose_kernel<<<BB * (VV / 32) * (UU / 32), 256, 0, stream>>>(pvc, pvcT);
    scores_kernel<<<BB * (QQ / 4) * (VV / 512), 256, 0, stream>>>(pqc, pvcT, vvec, esc);
    denom_kernel<<<BB * QQ, 256, 0, stream>>>(esc, denom);
    out_kernel<<<BB * (QQ / 4) * (VV / 512), 256, 0, stream>>>(esc, denom, values, out);
}

// Round 4
// 232.762 us; speedup vs baseline: 1.5973x; 1.0278x over previous
//
#include <hip/hip_runtime.h>

#define BB 4
#define QQ 256
#define VV 2048
#define HH 512
#define UU 128

// exp(x) = exp2(x*LOG2E); tanh arg scale folded into projections: C2E = 2*log2(e)
#define C2E   2.8853900817779268f
#define LOG2E 1.4426950408889634f

__device__ __forceinline__ void fma4(float4& a, float s, const float4& w) {
    a.x = fmaf(s, w.x, a.x);
    a.y = fmaf(s, w.y, a.y);
    a.z = fmaf(s, w.z, a.z);
    a.w = fmaf(s, w.w, a.w);
}
__device__ __forceinline__ float2 exp2_2(float2 x) {
    return make_float2(__builtin_amdgcn_exp2f(x.x), __builtin_amdgcn_exp2f(x.y));
}
__device__ __forceinline__ float2 rcp2(float2 x) {
    return make_float2(__builtin_amdgcn_rcpf(x.x), __builtin_amdgcn_rcpf(x.y));
}
__device__ __forceinline__ float2 add2(float2 a, float2 b) { return make_float2(a.x+b.x, a.y+b.y); }
__device__ __forceinline__ float2 adds(float2 a, float s)  { return make_float2(a.x+s, a.y+s); }
__device__ __forceinline__ float2 mul2(float2 a, float2 b) { return make_float2(a.x*b.x, a.y*b.y); }
__device__ __forceinline__ float2 fma2(float2 a, float2 b, float2 c) {
    return make_float2(fmaf(a.x, b.x, c.x), fmaf(a.y, b.y, c.y));
}
__device__ __forceinline__ float2 fmas(float2 a, float s, float2 c) {
    return make_float2(fmaf(a.x, s, c.x), fmaf(a.y, s, c.y));
}

// ---------------------------------------------------------------------------
// Projection GEMM, TRANSPOSED output: OT[u][r] = C2E * sum_h A[r][h]*W[h][u]
// 16 rows x 128 u per block, BK=32, W+A staged in LDS. LDS re-transpose at
// epilogue so stores are 64B-contiguous per u. grid = 512 (values) + 64 (q).
// pvT layout [b][u][VV], pqT layout [b][u][QQ].
// ---------------------------------------------------------------------------
__global__ __launch_bounds__(256) void proj_kernel(const float* __restrict__ queries,
                                                   const float* __restrict__ values,
                                                   const float* __restrict__ w1,
                                                   const float* __restrict__ w2,
                                                   float* __restrict__ pqT,
                                                   float* __restrict__ pvT) {
    __shared__ float As[32][18];     // [k][row]
    __shared__ float Ws[32 * 128];   // [k][u]
    __shared__ float Ls[128][17];    // [u][row] epilogue transpose
    const int bid = blockIdx.x;
    const float* A; const float* W; float* O; size_t OS;
    if (bid < 512) {                       // values: 8192 rows
        const int b = bid >> 7, r0 = (bid & 127) * 16;
        A = values + ((size_t)(b * VV + r0)) * HH;
        W = w2; O = pvT + (size_t)b * UU * VV + r0; OS = VV;
    } else {                               // queries: 1024 rows
        const int q = bid - 512;
        const int b = q >> 4, r0 = (q & 15) * 16;
        A = queries + ((size_t)(b * QQ + r0)) * HH;
        W = w1; O = pqT + (size_t)b * UU * QQ + r0; OS = QQ;
    }

    const int tid = threadIdx.x;
    const int tx = tid & 31;         // u-group: u = tx*4 .. tx*4+3
    const int ty = tid >> 5;         // row-pair: rows 2ty, 2ty+1
    float4 acc0 = make_float4(0.f, 0.f, 0.f, 0.f);
    float4 acc1 = make_float4(0.f, 0.f, 0.f, 0.f);

    for (int k0 = 0; k0 < HH; k0 += 32) {
        if (tid < 128) {             // A tile: 16 rows x 32 k, store transposed
            const int r = tid >> 3, kk4 = (tid & 7) * 4;
            const float4 a = *(const float4*)&A[(size_t)r * HH + k0 + kk4];
            As[kk4 + 0][r] = a.x; As[kk4 + 1][r] = a.y;
            As[kk4 + 2][r] = a.z; As[kk4 + 3][r] = a.w;
        }
#pragma unroll
        for (int t = 0; t < 4; t++) {  // W tile: 32 k x 128 u
            const int f = tid + t * 256;
            const int kk = f >> 5, u4 = (f & 31) * 4;
            *(float4*)&Ws[kk * 128 + u4] = *(const float4*)&W[(size_t)(k0 + kk) * UU + u4];
        }
        __syncthreads();
#pragma unroll
        for (int kk = 0; kk < 32; kk++) {
            const float2 a = *(const float2*)&As[kk][ty * 2];   // broadcast
            const float4 w = *(const float4*)&Ws[kk * 128 + tx * 4];
            fma4(acc0, a.x, w);
            fma4(acc1, a.y, w);
        }
        __syncthreads();
    }
    // epilogue: Ls[u][r] then coalesced transposed store
    {
        const float a0[4] = {acc0.x, acc0.y, acc0.z, acc0.w};
        const float a1[4] = {acc1.x, acc1.y, acc1.z, acc1.w};
#pragma unroll
        for (int i = 0; i < 4; i++) {
            Ls[tx * 4 + i][ty * 2 + 0] = a0[i] * C2E;
            Ls[tx * 4 + i][ty * 2 + 1] = a1[i] * C2E;
        }
    }
    __syncthreads();
    {
        const int uu = tid >> 1, half = (tid & 1) * 8;
        float4 o0, o1;
        o0.x = Ls[uu][half + 0]; o0.y = Ls[uu][half + 1];
        o0.z = Ls[uu][half + 2]; o0.w = Ls[uu][half + 3];
        o1.x = Ls[uu][half + 4]; o1.y = Ls[uu][half + 5];
        o1.z = Ls[uu][half + 6]; o1.w = Ls[uu][half + 7];
        float* dst = O + (size_t)uu * OS + half;
        *(float4*)dst = o0;
        *(float4*)(dst + 4) = o1;
    }
}

// ---------------------------------------------------------------------------
// Fused scores+softmax-numerator+out. grid = 4b * 32qb * 8vs = 1024.
// Phase A: esc[8q] for this lane's v via grouped-rcp tanh (4 u per v_rcp):
//   w0/(1+a)+w1/(1+b) = [w01 + w0*b + w1*a] / [(1+a)(1+b)]
// Phase B: out[b][q][h] += sum_v att[v][q]*values[v][h] (atomicAdd),
//   denom[b][q] += sum_v esc (atomicAdd). Normalization deferred.
// ---------------------------------------------------------------------------
__global__ __launch_bounds__(256) void fused_kernel(const float* __restrict__ pqT,
                                                    const float* __restrict__ pvT,
                                                    const float* __restrict__ vvec,
                                                    const float* __restrict__ values,
                                                    float* __restrict__ out,
                                                    float* __restrict__ denom) {
    __shared__ float att[256][8];    // [v][q] 8 KB
    __shared__ float red[8][512];    // [q][h] 16 KB (phase-B cross-half reduce)
    __shared__ float wred[4][8];     // per-wave denom partials
    const int tid = threadIdx.x;
    const int bid = blockIdx.x;
    const int vs = bid & 7, qb = (bid >> 3) & 31, b = bid >> 8;
    const int qbase = qb * 8, vbase = vs * 256;
    const int v = vbase + tid;       // this lane's v for phase A

    // uniform sum_u v[u]
    float vsum = 0.0f;
#pragma unroll
    for (int u4 = 0; u4 < UU; u4 += 4) {
        const float4 t = *(const float4*)&vvec[u4];
        vsum += t.x + t.y + t.z + t.w;
    }

    const float* pvp = pvT + (size_t)b * UU * VV + v;
    const float* pqp = pqT + (size_t)b * UU * QQ + qbase;   // [u][q], uniform

    float2 acc[4];
#pragma unroll
    for (int p = 0; p < 4; p++) acc[p] = make_float2(0.f, 0.f);

    for (int g = 0; g < 32; g++) {
        const int u = g * 4;
        const float pv0 = pvp[(size_t)(u + 0) * VV];
        const float pv1 = pvp[(size_t)(u + 1) * VV];
        const float pv2 = pvp[(size_t)(u + 2) * VV];
        const float pv3 = pvp[(size_t)(u + 3) * VV];
        const float4 wq = *(const float4*)&vvec[u];          // uniform (s_load)
        const float w0 = 2.f * wq.x, w1 = 2.f * wq.y;
        const float w2 = 2.f * wq.z, w3 = 2.f * wq.w;
        const float w01 = w0 + w1, w23 = w2 + w3;
#pragma unroll
        for (int p = 0; p < 4; p++) {
            const float2 pqa = *(const float2*)&pqp[(size_t)(u + 0) * QQ + 2 * p];
            const float2 pqb = *(const float2*)&pqp[(size_t)(u + 1) * QQ + 2 * p];
            const float2 pqc = *(const float2*)&pqp[(size_t)(u + 2) * QQ + 2 * p];
            const float2 pqd = *(const float2*)&pqp[(size_t)(u + 3) * QQ + 2 * p];
            const float2 ea = exp2_2(adds(pqa, pv0));
            const float2 eb = exp2_2(adds(pqb, pv1));
            const float2 ec = exp2_2(adds(pqc, pv2));
            const float2 ed = exp2_2(adds(pqd, pv3));
            const float2 a1 = adds(ea, 1.f), b1 = adds(eb, 1.f);
            const float2 c1 = adds(ec, 1.f), d1 = adds(ed, 1.f);
            const float2 pab = mul2(a1, b1), pcd = mul2(c1, d1);
            float2 nab = fmas(eb, w0, make_float2(w01, w01));
            nab = fmas(ea, w1, nab);
            float2 ncd = fmas(ed, w2, make_float2(w23, w23));
            ncd = fmas(ec, w3, ncd);
            const float2 num = fma2(nab, pcd, mul2(ncd, pab));
            const float2 den = mul2(pab, pcd);
            acc[p] = fma2(num, rcp2(den), acc[p]);
        }
    }

    // esc -> att LDS + per-wave denom reduce
#pragma unroll
    for (int p = 0; p < 4; p++) {
        float2 e;
        e.x = __builtin_amdgcn_exp2f((vsum - acc[p].x) * LOG2E);
        e.y = __builtin_amdgcn_exp2f((vsum - acc[p].y) * LOG2E);
        att[tid][2 * p + 0] = e.x;
        att[tid][2 * p + 1] = e.y;
        acc[p] = e;                  // reuse as esc for reduction
    }
#pragma unroll
    for (int off = 1; off < 64; off <<= 1) {
#pragma unroll
        for (int p = 0; p < 4; p++) {
            acc[p].x += __shfl_xor(acc[p].x, off, 64);
            acc[p].y += __shfl_xor(acc[p].y, off, 64);
        }
    }
    if ((tid & 63) == 0) {
        const int w = tid >> 6;
#pragma unroll
        for (int p = 0; p < 4; p++) {
            wred[w][2 * p + 0] = acc[p].x;
            wred[w][2 * p + 1] = acc[p].y;
        }
    }
    __syncthreads();
    if (tid < 8)
        atomicAdd(&denom[b * QQ + qbase + tid],
                  wred[0][tid] + wred[1][tid] + wred[2][tid] + wred[3][tid]);

    // Phase B: out accumulation over this block's 256 v
    const int hg = tid & 127, vh = tid >> 7;    // vh wave-uniform
    const int h0 = hg * 4;
    const float* vp = values + ((size_t)(b * VV + vbase + vh * 128)) * HH + h0;

    float4 oacc[8];
#pragma unroll
    for (int q = 0; q < 8; q++) oacc[q] = make_float4(0.f, 0.f, 0.f, 0.f);

#pragma unroll 2
    for (int vv = 0; vv < 128; vv++) {
        const float4 w = *(const float4*)&vp[(size_t)vv * HH];
        const float4 q0 = *(const float4*)&att[vh * 128 + vv][0];   // broadcast
        const float4 q1 = *(const float4*)&att[vh * 128 + vv][4];
        fma4(oacc[0], q0.x, w); fma4(oacc[1], q0.y, w);
        fma4(oacc[2], q0.z, w); fma4(oacc[3], q0.w, w);
        fma4(oacc[4], q1.x, w); fma4(oacc[5], q1.y, w);
        fma4(oacc[6], q1.z, w); fma4(oacc[7], q1.w, w);
    }

    if (vh == 1) {
#pragma unroll
        for (int q = 0; q < 8; q++) *(float4*)&red[q][h0] = oacc[q];
    }
    __syncthreads();
    if (vh == 0) {
#pragma unroll
        for (int q = 0; q < 8; q++) {
            const float4 p4 = *(const float4*)&red[q][h0];
            float* op = out + ((size_t)(b * QQ + qbase + q)) * HH + h0;
            atomicAdd(op + 0, oacc[q].x + p4.x);
            atomicAdd(op + 1, oacc[q].y + p4.y);
            atomicAdd(op + 2, oacc[q].z + p4.z);
            atomicAdd(op + 3, oacc[q].w + p4.w);
        }
    }
}

// ---------------------------------------------------------------------------
// out[i] *= rcp(denom[row]). 131072 float4s, grid 512.
// ---------------------------------------------------------------------------
__global__ __launch_bounds__(256) void normalize_kernel(float* __restrict__ out,
                                                        const float* __restrict__ denom) {
    const int i = blockIdx.x * 256 + threadIdx.x;
    float4 o = ((float4*)out)[i];
    const float r = __builtin_amdgcn_rcpf(denom[(i * 4) >> 9]);
    o.x *= r; o.y *= r; o.z *= r; o.w *= r;
    ((float4*)out)[i] = o;
}

// ---------------------------------------------------------------------------
extern "C" void kernel_launch(void* const* d_in, const int* in_sizes, int n_in,
                              void* d_out, int out_size, void* d_ws, size_t ws_size,
                              hipStream_t stream) {
    const float* queries = (const float*)d_in[0];  // [B,Q,H]
    const float* values  = (const float*)d_in[1];  // [B,V,H]
    const float* w1      = (const float*)d_in[2];  // [H,U]
    const float* w2      = (const float*)d_in[3];  // [H,U]
    const float* vvec    = (const float*)d_in[4];  // [U]
    float* out = (float*)d_out;

    // ws (floats): pqT[B*U*Q = 131072] | pvT[B*U*V = 1048576] | denom[1024]
    float* ws    = (float*)d_ws;
    float* pqT   = ws;
    float* pvT   = pqT + BB * UU * QQ;
    float* denom = pvT + (size_t)BB * UU * VV;

    hipMemsetAsync(d_out, 0, (size_t)out_size * sizeof(float), stream);
    hipMemsetAsync(denom, 0, BB * QQ * sizeof(float), stream);

    proj_kernel<<<512 + 64, 256, 0, stream>>>(queries, values, w1, w2, pqT, pvT);
    fused_kernel<<<BB * (QQ / 8) * (VV / 256), 256, 0, stream>>>(pqT, pvT, vvec, values, out, denom);
    normalize_kernel<<<(BB * QQ * HH) / 4 / 256, 256, 0, stream>>>(out, denom);
}

// Round 5
// 207.847 us; speedup vs baseline: 1.7888x; 1.1199x over previous
//
#include <hip/hip_runtime.h>

#define BB 4
#define QQ 256
#define VV 2048
#define HH 512
#define UU 128

// exp(x) = exp2(x*LOG2E); tanh arg scale folded into projections: C2E = 2*log2(e)
#define C2E   2.8853900817779268f
#define LOG2E 1.4426950408889634f

__device__ __forceinline__ void fma4(float4& a, float s, const float4& w) {
    a.x = fmaf(s, w.x, a.x);
    a.y = fmaf(s, w.y, a.y);
    a.z = fmaf(s, w.z, a.z);
    a.w = fmaf(s, w.w, a.w);
}
__device__ __forceinline__ float2 exp2_2(float2 x) {
    return make_float2(__builtin_amdgcn_exp2f(x.x), __builtin_amdgcn_exp2f(x.y));
}
__device__ __forceinline__ float2 rcp2(float2 x) {
    return make_float2(__builtin_amdgcn_rcpf(x.x), __builtin_amdgcn_rcpf(x.y));
}
__device__ __forceinline__ float2 adds(float2 a, float s)  { return make_float2(a.x+s, a.y+s); }
__device__ __forceinline__ float2 mul2(float2 a, float2 b) { return make_float2(a.x*b.x, a.y*b.y); }
__device__ __forceinline__ float2 fma2(float2 a, float2 b, float2 c) {
    return make_float2(fmaf(a.x, b.x, c.x), fmaf(a.y, b.y, c.y));
}
__device__ __forceinline__ float2 fmas(float2 a, float s, float2 c) {
    return make_float2(fmaf(a.x, s, c.x), fmaf(a.y, s, c.y));
}

// ---------------------------------------------------------------------------
// Projection GEMM, TRANSPOSED output: OT[u][r] = C2E * sum_h A[r][h]*W[h][u]
// 16 rows x 128 u per block, BK=32, W+A staged in LDS. grid = 512+64.
// pvT layout [b][u][VV], pqT layout [b][u][QQ].
// ---------------------------------------------------------------------------
__global__ __launch_bounds__(256) void proj_kernel(const float* __restrict__ queries,
                                                   const float* __restrict__ values,
                                                   const float* __restrict__ w1,
                                                   const float* __restrict__ w2,
                                                   float* __restrict__ pqT,
                                                   float* __restrict__ pvT) {
    __shared__ float As[32][18];     // [k][row]
    __shared__ float Ws[32 * 128];   // [k][u]
    __shared__ float Ls[128][17];    // [u][row] epilogue transpose
    const int bid = blockIdx.x;
    const float* A; const float* W; float* O; size_t OS;
    if (bid < 512) {                       // values: 8192 rows
        const int b = bid >> 7, r0 = (bid & 127) * 16;
        A = values + ((size_t)(b * VV + r0)) * HH;
        W = w2; O = pvT + (size_t)b * UU * VV + r0; OS = VV;
    } else {                               // queries: 1024 rows
        const int q = bid - 512;
        const int b = q >> 4, r0 = (q & 15) * 16;
        A = queries + ((size_t)(b * QQ + r0)) * HH;
        W = w1; O = pqT + (size_t)b * UU * QQ + r0; OS = QQ;
    }

    const int tid = threadIdx.x;
    const int tx = tid & 31;         // u-group: u = tx*4 .. tx*4+3
    const int ty = tid >> 5;         // row-pair: rows 2ty, 2ty+1
    float4 acc0 = make_float4(0.f, 0.f, 0.f, 0.f);
    float4 acc1 = make_float4(0.f, 0.f, 0.f, 0.f);

    for (int k0 = 0; k0 < HH; k0 += 32) {
        if (tid < 128) {             // A tile: 16 rows x 32 k, store transposed
            const int r = tid >> 3, kk4 = (tid & 7) * 4;
            const float4 a = *(const float4*)&A[(size_t)r * HH + k0 + kk4];
            As[kk4 + 0][r] = a.x; As[kk4 + 1][r] = a.y;
            As[kk4 + 2][r] = a.z; As[kk4 + 3][r] = a.w;
        }
#pragma unroll
        for (int t = 0; t < 4; t++) {  // W tile: 32 k x 128 u
            const int f = tid + t * 256;
            const int kk = f >> 5, u4 = (f & 31) * 4;
            *(float4*)&Ws[kk * 128 + u4] = *(const float4*)&W[(size_t)(k0 + kk) * UU + u4];
        }
        __syncthreads();
#pragma unroll
        for (int kk = 0; kk < 32; kk++) {
            const float2 a = *(const float2*)&As[kk][ty * 2];   // broadcast
            const float4 w = *(const float4*)&Ws[kk * 128 + tx * 4];
            fma4(acc0, a.x, w);
            fma4(acc1, a.y, w);
        }
        __syncthreads();
    }
    {
        const float a0[4] = {acc0.x, acc0.y, acc0.z, acc0.w};
        const float a1[4] = {acc1.x, acc1.y, acc1.z, acc1.w};
#pragma unroll
        for (int i = 0; i < 4; i++) {
            Ls[tx * 4 + i][ty * 2 + 0] = a0[i] * C2E;
            Ls[tx * 4 + i][ty * 2 + 1] = a1[i] * C2E;
        }
    }
    __syncthreads();
    {
        const int uu = tid >> 1, half = (tid & 1) * 8;
        float4 o0, o1;
        o0.x = Ls[uu][half + 0]; o0.y = Ls[uu][half + 1];
        o0.z = Ls[uu][half + 2]; o0.w = Ls[uu][half + 3];
        o1.x = Ls[uu][half + 4]; o1.y = Ls[uu][half + 5];
        o1.z = Ls[uu][half + 6]; o1.w = Ls[uu][half + 7];
        float* dst = O + (size_t)uu * OS + half;
        *(float4*)dst = o0;
        *(float4*)(dst + 4) = o1;
    }
}

// ---------------------------------------------------------------------------
// Fused scores+softmax-numerator+partial-out. grid = 4b * 32qb * 8vs = 1024.
// Phase A: esc[8q] per lane-v via grouped-rcp tanh (4 u share one v_rcp).
// Phase B: q-half split (no cross reduce); PLAIN stores to private slab[vs]
//   (R4 failure: cross-block atomicAdd -> 65MB HBM RMW ping-pong).
// denom[b][q] += sum_v esc via one atomic per block (tiny).
// ---------------------------------------------------------------------------
__global__ __launch_bounds__(256) void fused_kernel(const float* __restrict__ pqT,
                                                    const float* __restrict__ pvT,
                                                    const float* __restrict__ vvec,
                                                    const float* __restrict__ values,
                                                    float* __restrict__ slab,
                                                    float* __restrict__ denom) {
    __shared__ float att[256][8];    // [v][q] 8 KB
    __shared__ float wred[4][8];     // per-wave denom partials
    const int tid = threadIdx.x;
    const int bid = blockIdx.x;
    const int vs = bid & 7, qb = (bid >> 3) & 31, b = bid >> 8;
    const int qbase = qb * 8, vbase = vs * 256;
    const int v = vbase + tid;       // this lane's v for phase A

    // uniform sum_u v[u]
    float vsum = 0.0f;
#pragma unroll
    for (int u4 = 0; u4 < UU; u4 += 4) {
        const float4 t = *(const float4*)&vvec[u4];
        vsum += t.x + t.y + t.z + t.w;
    }

    const float* pvp = pvT + (size_t)b * UU * VV + v;
    const float* pqp = pqT + (size_t)b * UU * QQ + qbase;   // [u][q], uniform -> s_load

    float2 acc[4];
#pragma unroll
    for (int p = 0; p < 4; p++) acc[p] = make_float2(0.f, 0.f);

    for (int g = 0; g < 32; g++) {
        const int u = g * 4;
        const float pv0 = pvp[(size_t)(u + 0) * VV];
        const float pv1 = pvp[(size_t)(u + 1) * VV];
        const float pv2 = pvp[(size_t)(u + 2) * VV];
        const float pv3 = pvp[(size_t)(u + 3) * VV];
        const float4 wq = *(const float4*)&vvec[u];          // uniform (s_load)
        const float w0 = 2.f * wq.x, w1 = 2.f * wq.y;
        const float w2 = 2.f * wq.z, w3 = 2.f * wq.w;
        const float w01 = w0 + w1, w23 = w2 + w3;
#pragma unroll
        for (int p = 0; p < 4; p++) {
            const float2 pqa = *(const float2*)&pqp[(size_t)(u + 0) * QQ + 2 * p];
            const float2 pqb = *(const float2*)&pqp[(size_t)(u + 1) * QQ + 2 * p];
            const float2 pqc = *(const float2*)&pqp[(size_t)(u + 2) * QQ + 2 * p];
            const float2 pqd = *(const float2*)&pqp[(size_t)(u + 3) * QQ + 2 * p];
            const float2 ea = exp2_2(adds(pqa, pv0));
            const float2 eb = exp2_2(adds(pqb, pv1));
            const float2 ec = exp2_2(adds(pqc, pv2));
            const float2 ed = exp2_2(adds(pqd, pv3));
            const float2 a1 = adds(ea, 1.f), b1 = adds(eb, 1.f);
            const float2 c1 = adds(ec, 1.f), d1 = adds(ed, 1.f);
            const float2 pab = mul2(a1, b1), pcd = mul2(c1, d1);
            float2 nab = fmas(eb, w0, make_float2(w01, w01));
            nab = fmas(ea, w1, nab);
            float2 ncd = fmas(ed, w2, make_float2(w23, w23));
            ncd = fmas(ec, w3, ncd);
            const float2 num = fma2(nab, pcd, mul2(ncd, pab));
            const float2 den = mul2(pab, pcd);
            acc[p] = fma2(num, rcp2(den), acc[p]);
        }
    }

    // esc -> att LDS + per-wave denom reduce
#pragma unroll
    for (int p = 0; p < 4; p++) {
        float2 e;
        e.x = __builtin_amdgcn_exp2f((vsum - acc[p].x) * LOG2E);
        e.y = __builtin_amdgcn_exp2f((vsum - acc[p].y) * LOG2E);
        att[tid][2 * p + 0] = e.x;
        att[tid][2 * p + 1] = e.y;
        acc[p] = e;
    }
#pragma unroll
    for (int off = 1; off < 64; off <<= 1) {
#pragma unroll
        for (int p = 0; p < 4; p++) {
            acc[p].x += __shfl_xor(acc[p].x, off, 64);
            acc[p].y += __shfl_xor(acc[p].y, off, 64);
        }
    }
    if ((tid & 63) == 0) {
        const int w = tid >> 6;
#pragma unroll
        for (int p = 0; p < 4; p++) {
            wred[w][2 * p + 0] = acc[p].x;
            wred[w][2 * p + 1] = acc[p].y;
        }
    }
    __syncthreads();
    if (tid < 8)
        atomicAdd(&denom[b * QQ + qbase + tid],
                  wred[0][tid] + wred[1][tid] + wred[2][tid] + wred[3][tid]);

    // Phase B: q-half split; every thread covers all 256 v of this block.
    const int hg = tid & 127, qh = tid >> 7;    // qh wave-uniform (q 4*qh..4*qh+3)
    const int h0 = hg * 4;
    const float* vp = values + ((size_t)(b * VV + vbase)) * HH + h0;

    float4 oacc[4];
#pragma unroll
    for (int j = 0; j < 4; j++) oacc[j] = make_float4(0.f, 0.f, 0.f, 0.f);

#pragma unroll 2
    for (int vv = 0; vv < 256; vv++) {
        const float4 w = *(const float4*)&vp[(size_t)vv * HH];
        const float4 a = *(const float4*)&att[vv][qh * 4];   // broadcast b128
        fma4(oacc[0], a.x, w); fma4(oacc[1], a.y, w);
        fma4(oacc[2], a.z, w); fma4(oacc[3], a.w, w);
    }

    float* sp = slab + (size_t)vs * (BB * QQ * HH);
#pragma unroll
    for (int j = 0; j < 4; j++) {
        const int q = qh * 4 + j;
        *(float4*)&sp[((size_t)(b * QQ + qbase + q)) * HH + h0] = oacc[j];
    }
}

// ---------------------------------------------------------------------------
// out = (sum of 8 slabs) * rcp(denom[row]). 131072 float4s, grid 512.
// ---------------------------------------------------------------------------
__global__ __launch_bounds__(256) void reduce_kernel(const float* __restrict__ slab,
                                                     const float* __restrict__ denom,
                                                     float* __restrict__ out) {
    const int i = blockIdx.x * 256 + threadIdx.x;    // float4 index
    const float r = __builtin_amdgcn_rcpf(denom[(i * 4) >> 9]);
    const float4* s4 = (const float4*)slab;
    float4 s = s4[i];
#pragma unroll
    for (int k = 1; k < 8; k++) {
        const float4 p = s4[(size_t)k * (BB * QQ * HH / 4) + i];
        s.x += p.x; s.y += p.y; s.z += p.z; s.w += p.w;
    }
    s.x *= r; s.y *= r; s.z *= r; s.w *= r;
    ((float4*)out)[i] = s;
}

// ---------------------------------------------------------------------------
extern "C" void kernel_launch(void* const* d_in, const int* in_sizes, int n_in,
                              void* d_out, int out_size, void* d_ws, size_t ws_size,
                              hipStream_t stream) {
    const float* queries = (const float*)d_in[0];  // [B,Q,H]
    const float* values  = (const float*)d_in[1];  // [B,V,H]
    const float* w1      = (const float*)d_in[2];  // [H,U]
    const float* w2      = (const float*)d_in[3];  // [H,U]
    const float* vvec    = (const float*)d_in[4];  // [U]
    float* out = (float*)d_out;

    // ws (floats): pqT[131072] | pvT[1048576] | denom[1024] | slab[8*524288]
    // total ~21.5 MB
    float* ws    = (float*)d_ws;
    float* pqT   = ws;
    float* pvT   = pqT + BB * UU * QQ;
    float* denom = pvT + (size_t)BB * UU * VV;
    float* slab  = denom + BB * QQ;

    hipMemsetAsync(denom, 0, BB * QQ * sizeof(float), stream);

    proj_kernel<<<512 + 64, 256, 0, stream>>>(queries, values, w1, w2, pqT, pvT);
    fused_kernel<<<BB * (QQ / 8) * (VV / 256), 256, 0, stream>>>(pqT, pvT, vvec, values, slab, denom);
    reduce_kernel<<<(BB * QQ * HH) / 4 / 256, 256, 0, stream>>>(slab, denom, out);
}

// Round 6
// 200.615 us; speedup vs baseline: 1.8533x; 1.0360x over previous
//
#include <hip/hip_runtime.h>

#define BB 4
#define QQ 256
#define VV 2048
#define HH 512
#define UU 128

// exp(x) = exp2(x*LOG2E); tanh arg scale folded into projections: C2E = 2*log2(e)
#define C2E   2.8853900817779268f
#define LOG2E 1.4426950408889634f

__device__ __forceinline__ void fma4(float4& a, float s, const float4& w) {
    a.x = fmaf(s, w.x, a.x);
    a.y = fmaf(s, w.y, a.y);
    a.z = fmaf(s, w.z, a.z);
    a.w = fmaf(s, w.w, a.w);
}
__device__ __forceinline__ float2 exp2_2(float2 x) {
    return make_float2(__builtin_amdgcn_exp2f(x.x), __builtin_amdgcn_exp2f(x.y));
}
__device__ __forceinline__ float2 rcp2(float2 x) {
    return make_float2(__builtin_amdgcn_rcpf(x.x), __builtin_amdgcn_rcpf(x.y));
}
__device__ __forceinline__ float2 adds(float2 a, float s)  { return make_float2(a.x+s, a.y+s); }
__device__ __forceinline__ float2 mul2(float2 a, float2 b) { return make_float2(a.x*b.x, a.y*b.y); }
__device__ __forceinline__ float2 fma2(float2 a, float2 b, float2 c) {
    return make_float2(fmaf(a.x, b.x, c.x), fmaf(a.y, b.y, c.y));
}
__device__ __forceinline__ float2 fmas(float2 a, float s, float2 c) {
    return make_float2(fmaf(a.x, s, c.x), fmaf(a.y, s, c.y));
}

// ---------------------------------------------------------------------------
// Projection GEMM. 16 rows x 128 u per block, BK=32, W+A staged in LDS.
// grid = 512 (values) + 64 (queries).
// values output: INTERLEAVED pvT4 layout: elem (b, g, v, j) at
//   b*UU*VV + (g*VV + v)*4 + j   (g = u>>2, j = u&3)
//   -> fused phase A reads 4 consecutive u as ONE float4.
// queries output: pqT[b][u][QQ] (plain transposed, for scalar s_loads).
// ---------------------------------------------------------------------------
__global__ __launch_bounds__(256) void proj_kernel(const float* __restrict__ queries,
                                                   const float* __restrict__ values,
                                                   const float* __restrict__ w1,
                                                   const float* __restrict__ w2,
                                                   float* __restrict__ pqT,
                                                   float* __restrict__ pvT) {
    __shared__ float As[32][18];     // [k][row]
    __shared__ float Ws[32 * 128];   // [k][u]
    __shared__ float Ls[128][17];    // [u][row] epilogue transpose
    const int bid = blockIdx.x;
    const bool isv = (bid < 512);
    const float* A; const float* W; int b, r0;
    if (isv) {                             // values: 8192 rows
        b = bid >> 7; r0 = (bid & 127) * 16;
        A = values + ((size_t)(b * VV + r0)) * HH;  W = w2;
    } else {                               // queries: 1024 rows
        const int q = bid - 512;
        b = q >> 4; r0 = (q & 15) * 16;
        A = queries + ((size_t)(b * QQ + r0)) * HH; W = w1;
    }

    const int tid = threadIdx.x;
    const int tx = tid & 31;         // u-group: u = tx*4 .. tx*4+3
    const int ty = tid >> 5;         // row-pair: rows 2ty, 2ty+1
    float4 acc0 = make_float4(0.f, 0.f, 0.f, 0.f);
    float4 acc1 = make_float4(0.f, 0.f, 0.f, 0.f);

    for (int k0 = 0; k0 < HH; k0 += 32) {
        if (tid < 128) {             // A tile: 16 rows x 32 k, store transposed
            const int r = tid >> 3, kk4 = (tid & 7) * 4;
            const float4 a = *(const float4*)&A[(size_t)r * HH + k0 + kk4];
            As[kk4 + 0][r] = a.x; As[kk4 + 1][r] = a.y;
            As[kk4 + 2][r] = a.z; As[kk4 + 3][r] = a.w;
        }
#pragma unroll
        for (int t = 0; t < 4; t++) {  // W tile: 32 k x 128 u
            const int f = tid + t * 256;
            const int kk = f >> 5, u4 = (f & 31) * 4;
            *(float4*)&Ws[kk * 128 + u4] = *(const float4*)&W[(size_t)(k0 + kk) * UU + u4];
        }
        __syncthreads();
#pragma unroll
        for (int kk = 0; kk < 32; kk++) {
            const float2 a = *(const float2*)&As[kk][ty * 2];   // broadcast
            const float4 w = *(const float4*)&Ws[kk * 128 + tx * 4];
            fma4(acc0, a.x, w);
            fma4(acc1, a.y, w);
        }
        __syncthreads();
    }
    {
        const float a0[4] = {acc0.x, acc0.y, acc0.z, acc0.w};
        const float a1[4] = {acc1.x, acc1.y, acc1.z, acc1.w};
#pragma unroll
        for (int i = 0; i < 4; i++) {
            Ls[tx * 4 + i][ty * 2 + 0] = a0[i] * C2E;
            Ls[tx * 4 + i][ty * 2 + 1] = a1[i] * C2E;
        }
    }
    __syncthreads();
    if (isv) {
        // interleaved store: 512 float4 chunks, chunk idx -> (g = idx>>4, r = idx&15)
        float* Ob = pvT + (size_t)b * UU * VV;
#pragma unroll
        for (int t = 0; t < 2; t++) {
            const int idx = tid + t * 256;
            const int g = idx >> 4, r = idx & 15;
            float4 o;
            o.x = Ls[4 * g + 0][r]; o.y = Ls[4 * g + 1][r];
            o.z = Ls[4 * g + 2][r]; o.w = Ls[4 * g + 3][r];
            *(float4*)&Ob[((size_t)g * VV + r0 + r) * 4] = o;
        }
    } else {
        float* O = pqT + (size_t)b * UU * QQ + r0;
        const int uu = tid >> 1, half = (tid & 1) * 8;
        float4 o0, o1;
        o0.x = Ls[uu][half + 0]; o0.y = Ls[uu][half + 1];
        o0.z = Ls[uu][half + 2]; o0.w = Ls[uu][half + 3];
        o1.x = Ls[uu][half + 4]; o1.y = Ls[uu][half + 5];
        o1.z = Ls[uu][half + 6]; o1.w = Ls[uu][half + 7];
        float* dst = O + (size_t)uu * QQ + half;
        *(float4*)dst = o0;
        *(float4*)(dst + 4) = o1;
    }
}

// ---------------------------------------------------------------------------
// Fused scores+softmax-numerator+partial-out. grid = 4b*32qb*8vs = 1024,
// 512 threads (8 waves) for 32 waves/CU at 4 blocks/CU (R5: only 4 waves/SIMD
// -> 45% stall; this doubles TLP).
// Phase A: u-range split across thread halves (uh = tid>>8 handles 64 u);
//   grouped-rcp tanh (4 u per v_rcp); halves combined in LDS before exp.
// Phase B: (qh, vh) split across half-waves; LDS reduce over v-halves;
//   plain stores to private slab[vs].
// ---------------------------------------------------------------------------
__global__ __launch_bounds__(512, 8) void fused_kernel(const float* __restrict__ pqT,
                                                       const float* __restrict__ pvT,
                                                       const float* __restrict__ vvec,
                                                       const float* __restrict__ values,
                                                       float* __restrict__ slab,
                                                       float* __restrict__ denom) {
    __shared__ float att[256][8];    // [v][q] 8 KB, persists A->B
    __shared__ float red[8][512];    // 16 KB: phase-A combine (first 8KB) + phase-B reduce
    __shared__ float wred[4][8];
    const int tid = threadIdx.x;
    const int bid = blockIdx.x;
    const int vs = bid & 7, qb = (bid >> 3) & 31, b = bid >> 8;
    const int qbase = qb * 8, vbase = vs * 256;

    // ---- Phase A ----
    const int vloc = tid & 255, uh = tid >> 8;      // uh wave-uniform
    const int v = vbase + vloc;

    float vsum = 0.0f;
#pragma unroll
    for (int u4 = 0; u4 < UU; u4 += 4) {
        const float4 t = *(const float4*)&vvec[u4];
        vsum += t.x + t.y + t.z + t.w;
    }

    const float* pv4p = pvT + (size_t)b * UU * VV + (size_t)v * 4;
    const float* pqp  = pqT + (size_t)b * UU * QQ + qbase;   // wave-uniform -> s_load

    float2 acc[4];
#pragma unroll
    for (int p = 0; p < 4; p++) acc[p] = make_float2(0.f, 0.f);

    for (int g = 0; g < 16; g++) {
        const int G = uh * 16 + g;                  // global u-group
        const float4 pv = *(const float4*)&pv4p[(size_t)G * VV * 4];
        const float4 wq = *(const float4*)&vvec[G * 4];      // uniform
        const float w0 = 2.f * wq.x, w1 = 2.f * wq.y;
        const float w2 = 2.f * wq.z, w3 = 2.f * wq.w;
        const float w01 = w0 + w1, w23 = w2 + w3;
        const int u0 = G * 4;
#pragma unroll
        for (int p = 0; p < 4; p++) {
            const float2 pqa = *(const float2*)&pqp[(size_t)(u0 + 0) * QQ + 2 * p];
            const float2 pqb = *(const float2*)&pqp[(size_t)(u0 + 1) * QQ + 2 * p];
            const float2 pqc = *(const float2*)&pqp[(size_t)(u0 + 2) * QQ + 2 * p];
            const float2 pqd = *(const float2*)&pqp[(size_t)(u0 + 3) * QQ + 2 * p];
            const float2 ea = exp2_2(adds(pqa, pv.x));
            const float2 eb = exp2_2(adds(pqb, pv.y));
            const float2 ec = exp2_2(adds(pqc, pv.z));
            const float2 ed = exp2_2(adds(pqd, pv.w));
            const float2 a1 = adds(ea, 1.f), b1 = adds(eb, 1.f);
            const float2 c1 = adds(ec, 1.f), d1 = adds(ed, 1.f);
            const float2 pab = mul2(a1, b1), pcd = mul2(c1, d1);
            float2 nab = fmas(eb, w0, make_float2(w01, w01));
            nab = fmas(ea, w1, nab);
            float2 ncd = fmas(ed, w2, make_float2(w23, w23));
            ncd = fmas(ec, w3, ncd);
            const float2 num = fma2(nab, pcd, mul2(ncd, pab));
            const float2 den = mul2(pab, pcd);
            acc[p] = fma2(num, rcp2(den), acc[p]);
        }
    }

    // combine u-halves: upper half -> LDS, lower half finishes
    float* cbuf = &red[0][0];        // first 8 KB of red
    if (uh == 1) {
#pragma unroll
        for (int p = 0; p < 4; p++)
            *(float2*)&cbuf[vloc * 8 + 2 * p] = acc[p];
    }
    __syncthreads();
    if (uh == 0) {
#pragma unroll
        for (int p = 0; p < 4; p++) {
            const float2 hi = *(const float2*)&cbuf[vloc * 8 + 2 * p];
            float2 e;
            e.x = __builtin_amdgcn_exp2f((vsum - (acc[p].x + hi.x)) * LOG2E);
            e.y = __builtin_amdgcn_exp2f((vsum - (acc[p].y + hi.y)) * LOG2E);
            att[vloc][2 * p + 0] = e.x;
            att[vloc][2 * p + 1] = e.y;
            acc[p] = e;
        }
#pragma unroll
        for (int off = 1; off < 64; off <<= 1) {
#pragma unroll
            for (int p = 0; p < 4; p++) {
                acc[p].x += __shfl_xor(acc[p].x, off, 64);
                acc[p].y += __shfl_xor(acc[p].y, off, 64);
            }
        }
        if ((tid & 63) == 0) {
            const int w = tid >> 6;   // 0..3
#pragma unroll
            for (int p = 0; p < 4; p++) {
                wred[w][2 * p + 0] = acc[p].x;
                wred[w][2 * p + 1] = acc[p].y;
            }
        }
    }
    __syncthreads();
    if (tid < 8)
        atomicAdd(&denom[b * QQ + qbase + tid],
                  wred[0][tid] + wred[1][tid] + wred[2][tid] + wred[3][tid]);

    // ---- Phase B: (qh, vh) split across the 4 half-waves ----
    const int hg = tid & 127, sel = tid >> 7;       // sel wave-uniform
    const int qh = sel & 1, vh = sel >> 1;
    const int h0 = hg * 4;
    const float* vp = values + ((size_t)(b * VV + vbase + vh * 128)) * HH + h0;

    float4 oacc[4];
#pragma unroll
    for (int j = 0; j < 4; j++) oacc[j] = make_float4(0.f, 0.f, 0.f, 0.f);

#pragma unroll 2
    for (int vv = 0; vv < 128; vv++) {
        const float4 w = *(const float4*)&vp[(size_t)vv * HH];
        const float4 a = *(const float4*)&att[vh * 128 + vv][qh * 4];  // broadcast b128
        fma4(oacc[0], a.x, w); fma4(oacc[1], a.y, w);
        fma4(oacc[2], a.z, w); fma4(oacc[3], a.w, w);
    }

    if (vh == 1) {
#pragma unroll
        for (int j = 0; j < 4; j++) *(float4*)&red[qh * 4 + j][h0] = oacc[j];
    }
    __syncthreads();
    if (vh == 0) {
        float* sp = slab + (size_t)vs * (BB * QQ * HH);
#pragma unroll
        for (int j = 0; j < 4; j++) {
            const float4 p4 = *(const float4*)&red[qh * 4 + j][h0];
            const int q = qh * 4 + j;
            float4 o;
            o.x = oacc[j].x + p4.x; o.y = oacc[j].y + p4.y;
            o.z = oacc[j].z + p4.z; o.w = oacc[j].w + p4.w;
            *(float4*)&sp[((size_t)(b * QQ + qbase + q)) * HH + h0] = o;
        }
    }
}

// ---------------------------------------------------------------------------
// out = (sum of 8 slabs) * rcp(denom[row]). 131072 float4s, grid 512.
// ---------------------------------------------------------------------------
__global__ __launch_bounds__(256) void reduce_kernel(const float* __restrict__ slab,
                                                     const float* __restrict__ denom,
                                                     float* __restrict__ out) {
    const int i = blockIdx.x * 256 + threadIdx.x;    // float4 index
    const float r = __builtin_amdgcn_rcpf(denom[i >> 7]);
    const float4* s4 = (const float4*)slab;
    float4 s = s4[i];
#pragma unroll
    for (int k = 1; k < 8; k++) {
        const float4 p = s4[(size_t)k * (BB * QQ * HH / 4) + i];
        s.x += p.x; s.y += p.y; s.z += p.z; s.w += p.w;
    }
    s.x *= r; s.y *= r; s.z *= r; s.w *= r;
    ((float4*)out)[i] = s;
}

// ---------------------------------------------------------------------------
extern "C" void kernel_launch(void* const* d_in, const int* in_sizes, int n_in,
                              void* d_out, int out_size, void* d_ws, size_t ws_size,
                              hipStream_t stream) {
    const float* queries = (const float*)d_in[0];  // [B,Q,H]
    const float* values  = (const float*)d_in[1];  // [B,V,H]
    const float* w1      = (const float*)d_in[2];  // [H,U]
    const float* w2      = (const float*)d_in[3];  // [H,U]
    const float* vvec    = (const float*)d_in[4];  // [U]
    float* out = (float*)d_out;

    // ws (floats): pqT[131072] | pvT[1048576] | denom[1024] | slab[8*524288]
    float* ws    = (float*)d_ws;
    float* pqT   = ws;
    float* pvT   = pqT + BB * UU * QQ;
    float* denom = pvT + (size_t)BB * UU * VV;
    float* slab  = denom + BB * QQ;

    hipMemsetAsync(denom, 0, BB * QQ * sizeof(float), stream);

    proj_kernel<<<512 + 64, 256, 0, stream>>>(queries, values, w1, w2, pqT, pvT);
    fused_kernel<<<BB * (QQ / 8) * (VV / 256), 512, 0, stream>>>(pqT, pvT, vvec, values, slab, denom);
    reduce_kernel<<<(BB * QQ * HH) / 4 / 256, 256, 0, stream>>>(slab, denom, out);
}